// Round 5
// baseline (5169.567 us; speedup 1.0000x reference)
//
#include <hip/hip_runtime.h>

#define SEQ 2048
#define D 128

typedef float v2f __attribute__((ext_vector_type(2)));
typedef float v4f __attribute__((ext_vector_type(4)));
#define LO2(v) __builtin_shufflevector(v, v, 0, 1)
#define HI2(v) __builtin_shufflevector(v, v, 2, 3)

// ---------------------------------------------------------------------------
// Kernel 1: per-step J-independent quantities (fully parallel), UNNORMALIZED,
// extended with banded distance-d (d=1..3) products for the pair-fused scan:
//   kq_d[s][d-1] = k_{s-d} . q_s
//   vv_d[s][d-1] = v_s . v_{s-d}
//   kU_d[s][d-1] = k_{s-d} . U_s
// ---------------------------------------------------------------------------
__global__ __launch_bounds__(256) void precompute_kernel(
    const float* __restrict__ q, const float* __restrict__ k, const float* __restrict__ v,
    float* __restrict__ U, float* __restrict__ sl, float* __restrict__ kqq,
    float* __restrict__ vv, float* __restrict__ kq_adj, float* __restrict__ vv_adj,
    float* __restrict__ kU_adj, double* __restrict__ invl,
    float* __restrict__ kq_d, float* __restrict__ vv_d, float* __restrict__ kU_d)
{
    const int s = blockIdx.x;
    const int tid = threadIdx.x;

    __shared__ float ks[D];
    __shared__ float vs[D];
    __shared__ float alpha[SEQ];
    __shared__ float red[8];
    __shared__ float upart[256];

    if (tid < D) ks[tid] = k[s * D + tid];
    else if (tid < 2 * D) vs[tid - D] = v[s * D + (tid - D)];
    __syncthreads();

    float p_a2 = 0.f, p_ab = 0.f;
    for (int i = tid; i <= s; i += 256) {
        const float4* qr = (const float4*)(q + (size_t)i * D);
        const float4* vr = (const float4*)(v + (size_t)i * D);
        float a = 0.f, b = 0.f;
#pragma unroll
        for (int j = 0; j < D / 4; ++j) {
            float4 q4 = qr[j];
            float4 v4 = vr[j];
            a += q4.x * ks[4 * j + 0] + q4.y * ks[4 * j + 1] + q4.z * ks[4 * j + 2] + q4.w * ks[4 * j + 3];
            b += v4.x * vs[4 * j + 0] + v4.y * vs[4 * j + 1] + v4.z * vs[4 * j + 2] + v4.w * vs[4 * j + 3];
        }
        alpha[i] = a;
        p_a2 += a * a;
        p_ab += a * b;
        if (i == s) vv[s] = b;  // v_s . v_s
    }
#pragma unroll
    for (int off = 1; off < 64; off <<= 1) {
        p_a2 += __shfl_xor(p_a2, off);
        p_ab += __shfl_xor(p_ab, off);
    }
    const int wid = tid >> 6;
    if ((tid & 63) == 0) { red[wid] = p_a2; red[4 + wid] = p_ab; }
    __syncthreads();  // also makes alpha[] visible to everyone
    if (tid == 0) {
        kqq[s] = red[0] + red[1] + red[2] + red[3];
        sl[s]  = red[4] + red[5] + red[6] + red[7];
        invl[s] = 1.0 / (double)(s + 1);
    }

    // ---- banded dots: wave0 -> kq_d rows s+d; wave1 -> vv_d row s ----
    if (tid < 64) {
        for (int d = 1; d <= 3; ++d) {
            if (s + d < SEQ) {
                float p2 = ks[tid] * q[(size_t)(s + d) * D + tid]
                         + ks[tid + 64] * q[(size_t)(s + d) * D + 64 + tid];
#pragma unroll
                for (int off = 1; off < 64; off <<= 1) p2 += __shfl_xor(p2, off);
                if (tid == 0) kq_d[(size_t)(s + d) * 3 + (d - 1)] = p2;
            }
        }
        if (s == 0 && tid == 0) { kq_adj[0] = 0.f; kU_adj[0] = 0.f; vv_adj[0] = 0.f; }
    } else if (tid < 128) {
        const int t2 = tid - 64;
        for (int d = 1; d <= 3; ++d) {
            if (s - d >= 0) {
                float p2 = vs[t2] * v[(size_t)(s - d) * D + t2]
                         + vs[t2 + 64] * v[(size_t)(s - d) * D + 64 + t2];
#pragma unroll
                for (int off = 1; off < 64; off <<= 1) p2 += __shfl_xor(p2, off);
                if (t2 == 0) vv_d[(size_t)s * 3 + (d - 1)] = p2;
            }
        }
    }

    // pass 2: U[s][c] = sum_i q[i][c] * alpha[i]
    const int c = tid & (D - 1);
    const int h = tid >> 7;  // 0 or 1
    float a0 = 0.f, a1 = 0.f, a2 = 0.f, a3 = 0.f;
    int i = h;
    for (; i + 6 <= s; i += 8) {
        a0 = fmaf(q[(size_t)(i    ) * D + c], alpha[i    ], a0);
        a1 = fmaf(q[(size_t)(i + 2) * D + c], alpha[i + 2], a1);
        a2 = fmaf(q[(size_t)(i + 4) * D + c], alpha[i + 4], a2);
        a3 = fmaf(q[(size_t)(i + 6) * D + c], alpha[i + 6], a3);
    }
    for (; i <= s; i += 2) a0 = fmaf(q[(size_t)i * D + c], alpha[i], a0);
    upart[tid] = (a0 + a1) + (a2 + a3);
    __syncthreads();

    // U store + kU_d rows (d = 1..3)
    float uvv = 0.f;
    float kup = 0.f;
    if (tid < D) {
        uvv = upart[tid] + upart[tid + D];
        U[(size_t)s * D + tid] = uvv;
        if (s > 0) kup = uvv * k[(size_t)(s - 1) * D + tid];
    }
#pragma unroll
    for (int off = 1; off < 64; off <<= 1) kup += __shfl_xor(kup, off);
    if (tid == 0)  red[0] = kup;
    if (tid == 64) red[1] = kup;
    __syncthreads();
    if (s > 0 && tid == 0) {
        kU_adj[s] = red[0] + red[1];
        kU_d[(size_t)s * 3 + 0] = red[0] + red[1];
    }
    for (int d = 2; d <= 3; ++d) {
        float kd_ = 0.f;
        if (tid < D && s - d >= 0) kd_ = uvv * k[(size_t)(s - d) * D + tid];
#pragma unroll
        for (int off = 1; off < 64; off <<= 1) kd_ += __shfl_xor(kd_, off);
        __syncthreads();
        if (tid == 0)  red[0] = kd_;
        if (tid == 64) red[1] = kd_;
        __syncthreads();
        if (s - d >= 0 && tid == 0) kU_d[(size_t)s * 3 + (d - 1)] = red[0] + red[1];
    }
}

// ---------------------------------------------------------------------------
// DPP helpers (exact 16-lane cross-lane sums; no hidden scale factor).
// ---------------------------------------------------------------------------
#define DPP_ADD(x, ctrl) \
    ((x) + __int_as_float(__builtin_amdgcn_update_dpp(0, __float_as_int(x), (ctrl), 0xf, 0xf, true)))
#define REDUCE16(x) do { x = DPP_ADD(x, 0xB1); x = DPP_ADD(x, 0x4E); \
                         x = DPP_ADD(x, 0x141); x = DPP_ADD(x, 0x140); } while (0)

// Raw barrier WITHOUT vmcnt drain: per-wave DS ops drained (cross-wave LDS
// visibility), global prefetch loads stay in flight across barriers.
#define BARRIER() do { asm volatile("s_waitcnt lgkmcnt(0)" ::: "memory"); \
                       __builtin_amdgcn_s_barrier(); \
                       __builtin_amdgcn_sched_barrier(0); } while (0)

// fast fp64 reciprocal: v_rcp_f64 + 2 Newton iterations (~full precision)
static __device__ inline double fast_rcp(double d) {
    double r;
    asm("v_rcp_f64 %0, %1" : "=v"(r) : "v"(d));
    double e = __builtin_fma(-d, r, 1.0); r = __builtin_fma(r, e, r);
    e = __builtin_fma(-d, r, 1.0); r = __builtin_fma(r, e, r);
    return r;
}

// ---------------------------------------------------------------------------
// Kernel 2: sequential scan, 1024 threads (16 waves), ROUND-20.
// R19 falsified the clock theory; VALUBusy (~76% of the 1-CU ceiling) says the
// scan is VALU-ISSUE-bound: 8-way-redundant fp64 chains (4cy/instr issue) +
// fat dot phases saturate the 4 SIMDs. Restructure:
//   * PAIR-FUSED rounds: 2 steps per barrier round.
//   * waves 8..15: J owners -- per round: apply pair R-1's rank-2 update,
//     then 4 matvecs (Yq,Yw for both steps of pair R+1) vs the 1-pair-stale J,
//     + 11 reduction scalars into wred. NO fp64.
//   * wave 0: single decider -- chains BOTH decisions of pair R with exact
//     corrections for the <=3 in-flight rank-1s, using banded scalars
//     (kq_d/vv_d/kU_d, from kernel 1) + G-products (from the vector phase).
//   * waves 1-3,5-7: stagers (wave 4 idle, keeps SIMD0 light).
//   All three roles run CONCURRENTLY in one segment, one barrier/round:
//   writes go to slot P, reads come from slot PW=(P+2)%3 -- every cross-wave
//   handoff is separated by exactly one barrier.
// ---------------------------------------------------------------------------
__global__ __launch_bounds__(1024, 4) void scan_kernel(
    const float* __restrict__ q, const float* __restrict__ k, const float* __restrict__ v,
    const float* __restrict__ U, const float* __restrict__ sl_arr,
    const float* __restrict__ kqq_arr, const float* __restrict__ vv_arr,
    const float* __restrict__ qd_arr, const float* __restrict__ vvd_arr,
    const float* __restrict__ kud_arr, const double* __restrict__ invl_arr,
    float* __restrict__ out)  // [0,2048) costs | [2048,4096) updated | [4096,...) J
{
    const int tid  = threadIdx.x;
    const int lane = tid & 63;
    const int w    = __builtin_amdgcn_readfirstlane(tid >> 6);  // 0..15

    __shared__ float ring[3][8][160];   // [phase][q1,q2,u1,u2,k1,k2,v1,v2][swz]
    __shared__ __align__(16) float wred[3][32][12];
    __shared__ __align__(16) float decLDS[3][4];   // [phase][F,G1,G2,-]
    __shared__ float fsl[SEQ];
    __shared__ float fkq[SEQ];
    __shared__ float fvv[SEQ];
    __shared__ float fqd[SEQ * 3];
    __shared__ float fvd[SEQ * 3];
    __shared__ float fkd[SEQ * 3];
    __shared__ __align__(16) double finv[SEQ];

    // ---- roles ----
    const bool isj = (tid >= 512);                 // waves 8..15
    const int  jw  = w - 8;
    const int  i16 = lane & 15;
    const int  r4  = lane >> 4;
    const int  o   = 20 * (i16 >> 1) + 8 * (i16 & 1);
    const int  rb  = (jw << 4) + (r4 << 2);
    const int  vo  = 20 * jw + (r4 << 2);

    const bool stager = (tid >= 64 && tid < 256) || (tid >= 320 && tid < 512);
    const int  st     = (tid < 256) ? tid - 64 : tid - 128;   // 0..383

    // ---- feed copies to LDS ----
    if (tid < 512) {
        ((float4*)fsl)[tid] = ((const float4*)sl_arr)[tid];
        ((float4*)fkq)[tid] = ((const float4*)kqq_arr)[tid];
        ((float4*)fvv)[tid] = ((const float4*)vv_arr)[tid];
    }
    ((double2*)finv)[tid] = ((const double2*)invl_arr)[tid];
    for (int i = tid; i < SEQ * 3 / 4; i += 1024) {
        ((float4*)fqd)[i] = ((const float4*)qd_arr)[i];
        ((float4*)fvd)[i] = ((const float4*)vvd_arr)[i];
        ((float4*)fkd)[i] = ((const float4*)kud_arr)[i];
    }

    // ---- J tile + carried fragments ----
    v2f jA0 = {0.f, 0.f}, jA1 = jA0, jA2 = jA0, jA3 = jA0;
    v2f jB0 = jA0, jB1 = jA0, jB2 = jA0, jB3 = jA0;
    v2f jC0 = jA0, jC1 = jA0, jC2 = jA0, jC3 = jA0;
    v2f jD0 = jA0, jD1 = jA0, jD2 = jA0, jD3 = jA0;
    v4f Q1a = {0,0,0,0}, Q1b = Q1a, Q2a = Q1a, Q2b = Q1a;
    v4f U1a = Q1a, U1b = Q1a, U2a = Q1a, U2b = Q1a;
    v4f kA1a = Q1a, kA1b = Q1a, kA2a = Q1a, kA2b = Q1a;   // pair R-1 k frags
    v4f kB1a = Q1a, kB1b = Q1a, kB2a = Q1a, kB2b = Q1a;   // pair R   k frags
    v4f vA1 = Q1a, vA2 = Q1a, vB1 = Q1a, vB2 = Q1a;       // pair R-1 / R v

    // stager prefetch pipelines (phase-indexed, static after unroll)
    float g0[3] = {0, 0, 0}, g1[3] = {0, 0, 0}, g2[3] = {0, 0, 0};

    // decider fp64 state
    double SJ = 0.0, AJJ = 0.0, trSvv = 0.0;
    double fa = 1.0, ga = 0.0, fb = 1.0, gb = 0.0;   // pending pair's decs

#define MATVEC(Xa, Xb, RA, RB, RC, RD)                                        \
    {                                                                         \
        const v2f x0 = LO2(Xa), x1 = HI2(Xa), x2 = LO2(Xb), x3 = HI2(Xb);     \
        v2f tA = jA0 * x0, tB = jB0 * x0, tC = jC0 * x0, tD = jD0 * x0;       \
        tA = __builtin_elementwise_fma(jA1, x1, tA);                          \
        tB = __builtin_elementwise_fma(jB1, x1, tB);                          \
        tC = __builtin_elementwise_fma(jC1, x1, tC);                          \
        tD = __builtin_elementwise_fma(jD1, x1, tD);                          \
        tA = __builtin_elementwise_fma(jA2, x2, tA);                          \
        tB = __builtin_elementwise_fma(jB2, x2, tB);                          \
        tC = __builtin_elementwise_fma(jC2, x2, tC);                          \
        tD = __builtin_elementwise_fma(jD2, x2, tD);                          \
        tA = __builtin_elementwise_fma(jA3, x3, tA);                          \
        tB = __builtin_elementwise_fma(jB3, x3, tB);                          \
        tC = __builtin_elementwise_fma(jC3, x3, tC);                          \
        tD = __builtin_elementwise_fma(jD3, x3, tD);                          \
        RA = tA.x + tA.y; RB = tB.x + tB.y; RC = tC.x + tC.y; RD = tD.x + tD.y; \
    }

// vector phase: 4 matvecs + 11 reduction partials -> wred[P_]
#define DOTPHASE(P_)                                                          \
    {                                                                         \
        float Yq1A, Yq1B, Yq1C, Yq1D, Yq2A, Yq2B, Yq2C, Yq2D;                 \
        float W1A, W1B, W1C, W1D, W2A, W2B, W2C, W2D;                         \
        MATVEC(Q1a, Q1b, Yq1A, Yq1B, Yq1C, Yq1D)                              \
        MATVEC(Q2a, Q2b, Yq2A, Yq2B, Yq2C, Yq2D)                              \
        MATVEC(U1a, U1b, W1A, W1B, W1C, W1D)                                  \
        MATVEC(U2a, U2b, W2A, W2B, W2C, W2D)                                  \
        REDUCE16(Yq1A); REDUCE16(Yq1B); REDUCE16(Yq1C); REDUCE16(Yq1D);       \
        REDUCE16(Yq2A); REDUCE16(Yq2B); REDUCE16(Yq2C); REDUCE16(Yq2D);       \
        float pb11 = vB1.x * Yq1A + vB1.y * Yq1B + vB1.z * Yq1C + vB1.w * Yq1D; \
        float pb21 = Yq1A * Yq1A + Yq1B * Yq1B + Yq1C * Yq1C + Yq1D * Yq1D;   \
        float pb41 = vB1.x * W1A + vB1.y * W1B + vB1.z * W1C + vB1.w * W1D;   \
        REDUCE16(pb41);                                                       \
        float pg11 = vA1.x * Yq1A + vA1.y * Yq1B + vA1.z * Yq1C + vA1.w * Yq1D; \
        float pg21 = vA2.x * Yq1A + vA2.y * Yq1B + vA2.z * Yq1C + vA2.w * Yq1D; \
        float pb12 = vB2.x * Yq2A + vB2.y * Yq2B + vB2.z * Yq2C + vB2.w * Yq2D; \
        float pb22 = Yq2A * Yq2A + Yq2B * Yq2B + Yq2C * Yq2C + Yq2D * Yq2D;   \
        float pb42 = vB2.x * W2A + vB2.y * W2B + vB2.z * W2C + vB2.w * W2D;   \
        REDUCE16(pb42);                                                       \
        float pg12 = vA1.x * Yq2A + vA1.y * Yq2B + vA1.z * Yq2C + vA1.w * Yq2D; \
        float pg22 = vA2.x * Yq2A + vA2.y * Yq2B + vA2.z * Yq2C + vA2.w * Yq2D; \
        float pg3  = vB1.x * Yq2A + vB1.y * Yq2B + vB1.z * Yq2C + vB1.w * Yq2D; \
        if ((lane & 15) == 15) {                                              \
            const int e_ = (jw << 2) | r4;                                    \
            *(float4*)&wred[P_][e_][0] = make_float4(pb11, pb21, pb41, pg11); \
            *(float4*)&wred[P_][e_][4] = make_float4(pg21, pb12, pb22, pb42); \
            *(float4*)&wred[P_][e_][8] = make_float4(pg12, pg22, pg3, 0.f);   \
        }                                                                     \
    }

// apply pair rank-2 update: J = F*J + G1*vA1 kA1^T + G2*vA2 kA2^T
#define J_UPDATE(PW_)                                                         \
    {                                                                         \
        const float4 df_ = *(const float4*)&decLDS[PW_][0];                   \
        const float F_ = df_.x, Ga_ = df_.y, Gb_ = df_.z;                     \
        if (!(F_ == 1.f && Ga_ == 0.f && Gb_ == 0.f)) {                       \
            const v2f F2_ = {F_, F_};                                         \
            const v2f k10 = LO2(kA1a), k11 = HI2(kA1a), k12 = LO2(kA1b), k13 = HI2(kA1b); \
            const v2f k20 = LO2(kA2a), k21 = HI2(kA2a), k22 = LO2(kA2b), k23 = HI2(kA2b); \
            { const float w1 = Ga_ * vA1.x, w2 = Gb_ * vA2.x;                 \
              const v2f w1_ = {w1, w1}, w2_ = {w2, w2};                       \
              jA0 = __builtin_elementwise_fma(jA0, F2_, __builtin_elementwise_fma(w1_, k10, w2_ * k20)); \
              jA1 = __builtin_elementwise_fma(jA1, F2_, __builtin_elementwise_fma(w1_, k11, w2_ * k21)); \
              jA2 = __builtin_elementwise_fma(jA2, F2_, __builtin_elementwise_fma(w1_, k12, w2_ * k22)); \
              jA3 = __builtin_elementwise_fma(jA3, F2_, __builtin_elementwise_fma(w1_, k13, w2_ * k23)); } \
            { const float w1 = Ga_ * vA1.y, w2 = Gb_ * vA2.y;                 \
              const v2f w1_ = {w1, w1}, w2_ = {w2, w2};                       \
              jB0 = __builtin_elementwise_fma(jB0, F2_, __builtin_elementwise_fma(w1_, k10, w2_ * k20)); \
              jB1 = __builtin_elementwise_fma(jB1, F2_, __builtin_elementwise_fma(w1_, k11, w2_ * k21)); \
              jB2 = __builtin_elementwise_fma(jB2, F2_, __builtin_elementwise_fma(w1_, k12, w2_ * k22)); \
              jB3 = __builtin_elementwise_fma(jB3, F2_, __builtin_elementwise_fma(w1_, k13, w2_ * k23)); } \
            { const float w1 = Ga_ * vA1.z, w2 = Gb_ * vA2.z;                 \
              const v2f w1_ = {w1, w1}, w2_ = {w2, w2};                       \
              jC0 = __builtin_elementwise_fma(jC0, F2_, __builtin_elementwise_fma(w1_, k10, w2_ * k20)); \
              jC1 = __builtin_elementwise_fma(jC1, F2_, __builtin_elementwise_fma(w1_, k11, w2_ * k21)); \
              jC2 = __builtin_elementwise_fma(jC2, F2_, __builtin_elementwise_fma(w1_, k12, w2_ * k22)); \
              jC3 = __builtin_elementwise_fma(jC3, F2_, __builtin_elementwise_fma(w1_, k13, w2_ * k23)); } \
            { const float w1 = Ga_ * vA1.w, w2 = Gb_ * vA2.w;                 \
              const v2f w1_ = {w1, w1}, w2_ = {w2, w2};                       \
              jD0 = __builtin_elementwise_fma(jD0, F2_, __builtin_elementwise_fma(w1_, k10, w2_ * k20)); \
              jD1 = __builtin_elementwise_fma(jD1, F2_, __builtin_elementwise_fma(w1_, k11, w2_ * k21)); \
              jD2 = __builtin_elementwise_fma(jD2, F2_, __builtin_elementwise_fma(w1_, k12, w2_ * k22)); \
              jD3 = __builtin_elementwise_fma(jD3, F2_, __builtin_elementwise_fma(w1_, k13, w2_ * k23)); } \
        }                                                                     \
    }

// one decision: consumes z's already folded into SJ/AJJ + AJl; yields f,g,mode
#define DECIDE(S_L, A_LL, AJL, FO, GO, MO)                                    \
    {                                                                         \
        const double s_l_ = (S_L), A_ll_ = (A_LL), AJl_ = (AJL);              \
        const double AJJ_s_ = (AJJ == 0.0) ? 1.0 : AJJ;                       \
        const double A_ll_s_ = (A_ll_ == 0.0) ? 1.0 : A_ll_;                  \
        const double denom_ = AJJ * A_ll_ - AJl_ * AJl_;                      \
        const double denom_s_ = (denom_ == 0.0) ? 1.0 : denom_;               \
        const double rden_ = fast_rcp(denom_s_);                              \
        const double wf_ = (A_ll_ * SJ - AJl_ * s_l_) * rden_;                \
        const double wi_ = (AJJ * s_l_ - AJl_ * SJ) * rden_;                  \
        double wfc_, wic_;                                                    \
        if (wi_ <= 0.0)      { wfc_ = SJ / AJJ_s_;  wic_ = 0.0; }             \
        else if (wf_ <= 0.0) { wfc_ = 0.0;          wic_ = s_l_ / A_ll_s_; }  \
        else                 { wfc_ = wf_;          wic_ = wi_; }             \
        if ((s_l_ * AJJ_s_ - AJl_ * SJ) > 0.0) {                              \
            MO = 1;                                                           \
            const double nSJ_ = wfc_ * SJ + wic_ * s_l_;                      \
            AJJ = wfc_ * wfc_ * AJJ + 2.0 * wfc_ * wic_ * AJl_                \
                + wic_ * wic_ * A_ll_;                                        \
            SJ = nSJ_; FO = wfc_; GO = wic_;                                  \
        } else { MO = 0; FO = 1.0; GO = 0.0; }                                \
    }

// decider: reduce wred[PW] + chain both decisions of pair R
#define DECIDER(R, P_, PW_, LAST)                                             \
    {                                                                         \
        const int s1 = 2 * (R) + 1;                                           \
        const int s2c = ((LAST)) ? SEQ - 1 : 2 * (R) + 2;                     \
        const int la = lane & 15;                                             \
        const float4 e0 = *(const float4*)&wred[PW_][la][0];                  \
        const float4 e1 = *(const float4*)&wred[PW_][la][4];                  \
        const float4 e2 = *(const float4*)&wred[PW_][la][8];                  \
        const float4 h0 = *(const float4*)&wred[PW_][16 + la][0];             \
        const float4 h1 = *(const float4*)&wred[PW_][16 + la][4];             \
        const float4 h2 = *(const float4*)&wred[PW_][16 + la][8];             \
        float B1_1 = e0.x + h0.x, B2_1 = e0.y + h0.y, B4_1 = e0.z + h0.z;     \
        float G1_1 = e0.w + h0.w, G2_1 = e1.x + h1.x, B1_2 = e1.y + h1.y;     \
        float B2_2 = e1.z + h1.z, B4_2 = e1.w + h1.w, G1_2 = e2.x + h2.x;     \
        float G2_2 = e2.y + h2.y, G3f = e2.z + h2.z;                          \
        REDUCE16(B1_1); REDUCE16(B2_1); REDUCE16(B4_1); REDUCE16(G1_1);       \
        REDUCE16(G2_1); REDUCE16(B1_2); REDUCE16(B2_2); REDUCE16(B4_2);       \
        REDUCE16(G1_2); REDUCE16(G2_2); REDUCE16(G3f);                        \
        const int ia = (s1 >= 2) ? s1 - 2 : 0;                                \
        const double vva = (double)fvv[ia];                                   \
        const double vvb = (double)fvv[s1 - 1];                               \
        const double vab = (double)fvd[(s1 - 1) * 3 + 0];                     \
        const double qd1_1 = (double)fqd[s1 * 3 + 0], qd1_2 = (double)fqd[s1 * 3 + 1]; \
        const double vd1_1 = (double)fvd[s1 * 3 + 0], vd1_2 = (double)fvd[s1 * 3 + 1]; \
        const double kd1_1 = (double)fkd[s1 * 3 + 0], kd1_2 = (double)fkd[s1 * 3 + 1]; \
        const double sl1 = (double)fsl[s1], kq1 = (double)fkq[s1], vv1 = (double)fvv[s1]; \
        const double qd2_1 = (double)fqd[s2c * 3 + 0], qd2_2 = (double)fqd[s2c * 3 + 1], qd2_3 = (double)fqd[s2c * 3 + 2]; \
        const double vd2_1 = (double)fvd[s2c * 3 + 0], vd2_2 = (double)fvd[s2c * 3 + 1], vd2_3 = (double)fvd[s2c * 3 + 2]; \
        const double kd2_1 = (double)fkd[s2c * 3 + 0], kd2_2 = (double)fkd[s2c * 3 + 1], kd2_3 = (double)fkd[s2c * 3 + 2]; \
        const double sl2 = (double)fsl[s2c], kq2 = (double)fkq[s2c], vv2 = (double)fvv[s2c]; \
        const double inv1 = finv[s1], inv2 = finv[s2c];                       \
        const double A = fa * fb, Ca = fb * ga, Cb = gb;                      \
        const double z1 = A * (double)B1_1 + Ca * (vd1_2 * qd1_2)             \
                        + Cb * (vd1_1 * qd1_1);                               \
        const double z2 = A * A * (double)B2_1                                \
                        + Ca * Ca * qd1_2 * qd1_2 * vva                       \
                        + Cb * Cb * qd1_1 * qd1_1 * vvb                       \
                        + 2.0 * A * (Ca * qd1_2 * (double)G1_1                \
                                     + Cb * qd1_1 * (double)G2_1)             \
                        + 2.0 * Ca * Cb * qd1_2 * qd1_1 * vab;                \
        const double z4 = A * (double)B4_1 + Ca * vd1_2 * kd1_2               \
                        + Cb * vd1_1 * kd1_1;                                 \
        SJ += z1; AJJ += z2; trSvv += vv1;                                    \
        double f1, g1; int mode1;                                             \
        DECIDE(sl1, vv1 * kq1, z4, f1, g1, mode1)                             \
        const double cost1 = (0.5 * trSvv - SJ + 0.5 * AJJ) * inv1;           \
        const double A2 = f1 * A, Ca2 = f1 * Ca, Cb2 = f1 * Cb, Cc2 = g1;     \
        double f2 = 1.0, g2 = 0.0; int mode2 = 0; double cost2 = 0.0;         \
        if (!(LAST)) {                                                        \
            const double y1 = A2 * (double)B1_2 + Ca2 * vd2_3 * qd2_3         \
                            + Cb2 * vd2_2 * qd2_2 + Cc2 * vd2_1 * qd2_1;      \
            const double y2 = A2 * A2 * (double)B2_2                          \
                            + Ca2 * Ca2 * qd2_3 * qd2_3 * vva                 \
                            + Cb2 * Cb2 * qd2_2 * qd2_2 * vvb                 \
                            + Cc2 * Cc2 * qd2_1 * qd2_1 * vv1                 \
                            + 2.0 * A2 * (Ca2 * qd2_3 * (double)G1_2          \
                                          + Cb2 * qd2_2 * (double)G2_2        \
                                          + Cc2 * qd2_1 * (double)G3f)        \
                            + 2.0 * (Ca2 * Cb2 * qd2_3 * qd2_2 * vab          \
                                     + Ca2 * Cc2 * qd2_3 * qd2_1 * vd1_2      \
                                     + Cb2 * Cc2 * qd2_2 * qd2_1 * vd1_1);    \
            const double y4 = A2 * (double)B4_2 + Ca2 * vd2_3 * kd2_3         \
                            + Cb2 * vd2_2 * kd2_2 + Cc2 * vd2_1 * kd2_1;      \
            SJ += y1; AJJ += y2; trSvv += vv2;                                \
            DECIDE(sl2, vv2 * kq2, y4, f2, g2, mode2)                         \
            cost2 = (0.5 * trSvv - SJ + 0.5 * AJJ) * inv2;                    \
        }                                                                     \
        fa = f1; ga = g1; fb = f2; gb = g2;                                   \
        if (lane == 0) {                                                      \
            out[s1] = (float)cost1; out[SEQ + s1] = mode1 ? 1.f : 0.f;        \
            if (!(LAST)) {                                                    \
                out[s2c] = (float)cost2; out[SEQ + s2c] = mode2 ? 1.f : 0.f;  \
            }                                                                 \
            *(float4*)&decLDS[P_][0] = make_float4(                           \
                (float)(f1 * f2), (float)(g1 * f2), (float)g2, 0.f);          \
        }                                                                     \
    }

#define ST_ONE(SLOT, GARR, R, PW_)                                            \
    { const int s_ = (SLOT); const int a_ = s_ >> 7, c_ = s_ & 127;           \
      const int wix = (c_ >> 4) * 20 + (c_ & 15);                             \
      ring[PW_][a_][wix] = GARR[PW_];                                         \
      const float* b_ = (a_ < 2) ? q : (a_ < 4) ? U : (a_ < 6) ? k : v;       \
      int stp = 2 * ((R) + 6) + 1 + (a_ & 1);                                 \
      if (stp > SEQ - 1) stp = SEQ - 1;                                       \
      GARR[PW_] = b_[(size_t)stp * D + c_]; }

#define STAGE(R, PW_)                                                         \
    {                                                                         \
        ST_ONE(st, g0, R, PW_)                                                \
        ST_ONE(st + 384, g1, R, PW_)                                          \
        if (st < 256) ST_ONE(st + 768, g2, R, PW_)                            \
    }

#define ROUND(R, P_, PN_, PW_, LAST)                                          \
    {                                                                         \
        if (isj) {                                                            \
            J_UPDATE(PW_)                                                     \
            vA1 = vB1; vA2 = vB2;                                             \
            kA1a = kB1a; kA1b = kB1b; kA2a = kB2a; kA2b = kB2b;               \
            Q1a = ((const v4f*)&ring[P_][0][o])[0];                           \
            Q1b = ((const v4f*)&ring[P_][0][o])[1];                           \
            Q2a = ((const v4f*)&ring[P_][1][o])[0];                           \
            Q2b = ((const v4f*)&ring[P_][1][o])[1];                           \
            U1a = ((const v4f*)&ring[P_][2][o])[0];                           \
            U1b = ((const v4f*)&ring[P_][2][o])[1];                           \
            U2a = ((const v4f*)&ring[P_][3][o])[0];                           \
            U2b = ((const v4f*)&ring[P_][3][o])[1];                           \
            kB1a = ((const v4f*)&ring[P_][4][o])[0];                          \
            kB1b = ((const v4f*)&ring[P_][4][o])[1];                          \
            kB2a = ((const v4f*)&ring[P_][5][o])[0];                          \
            kB2b = ((const v4f*)&ring[P_][5][o])[1];                          \
            vB1 = *(const v4f*)&ring[P_][6][vo];                              \
            vB2 = *(const v4f*)&ring[P_][7][vo];                              \
            DOTPHASE(P_)                                                      \
        } else if (w == 0) {                                                  \
            DECIDER(R, P_, PW_, LAST)                                         \
        } else if (stager) {                                                  \
            STAGE(R, PW_)                                                     \
        }                                                                     \
        BARRIER();                                                            \
    }

    // ---- prologue ----
#define PRO_ONE(SLOT, GARR)                                                   \
    { const int s_ = (SLOT); const int a_ = s_ >> 7, c_ = s_ & 127;           \
      const int wix = (c_ >> 4) * 20 + (c_ & 15);                             \
      const float* b_ = (a_ < 2) ? q : (a_ < 4) ? U : (a_ < 6) ? k : v;       \
      const int o_ = (a_ & 1);                                                \
      ring[0][a_][wix] = b_[(size_t)(3 + o_) * D + c_];                       \
      ring[1][a_][wix] = b_[(size_t)(5 + o_) * D + c_];                       \
      GARR[2] = b_[(size_t)(7 + o_) * D + c_];                                \
      GARR[0] = b_[(size_t)(9 + o_) * D + c_];                                \
      GARR[1] = b_[(size_t)(11 + o_) * D + c_]; }

    if (stager) {
        PRO_ONE(st, g0)
        PRO_ONE(st + 384, g1)
        if (st < 256) PRO_ONE(st + 768, g2)
    } else if (isj) {
        // J init = v_0 k_0^T (dec_0, mode 2)
        const v4f v0  = *(const v4f*)&v[rb];
        const v4f K0a = *(const v4f*)&k[8 * i16];
        const v4f K0b = *(const v4f*)&k[8 * i16 + 4];
        const v2f k0_ = LO2(K0a), k1_ = HI2(K0a), k2_ = LO2(K0b), k3_ = HI2(K0b);
        const v2f wA = {v0.x, v0.x}, wB = {v0.y, v0.y};
        const v2f wC = {v0.z, v0.z}, wD = {v0.w, v0.w};
        jA0 = wA * k0_; jA1 = wA * k1_; jA2 = wA * k2_; jA3 = wA * k3_;
        jB0 = wB * k0_; jB1 = wB * k1_; jB2 = wB * k2_; jB3 = wB * k3_;
        jC0 = wC * k0_; jC1 = wC * k1_; jC2 = wC * k2_; jC3 = wC * k3_;
        jD0 = wD * k0_; jD1 = wD * k1_; jD2 = wD * k2_; jD3 = wD * k3_;
        // pair-0 fragments from global + pair-0 dots into wred[2]
        Q1a = *(const v4f*)&q[D + 8 * i16];     Q1b = *(const v4f*)&q[D + 8 * i16 + 4];
        Q2a = *(const v4f*)&q[2 * D + 8 * i16]; Q2b = *(const v4f*)&q[2 * D + 8 * i16 + 4];
        U1a = *(const v4f*)&U[D + 8 * i16];     U1b = *(const v4f*)&U[D + 8 * i16 + 4];
        U2a = *(const v4f*)&U[2 * D + 8 * i16]; U2b = *(const v4f*)&U[2 * D + 8 * i16 + 4];
        kB1a = *(const v4f*)&k[D + 8 * i16];     kB1b = *(const v4f*)&k[D + 8 * i16 + 4];
        kB2a = *(const v4f*)&k[2 * D + 8 * i16]; kB2b = *(const v4f*)&k[2 * D + 8 * i16 + 4];
        vB1 = *(const v4f*)&v[D + rb];
        vB2 = *(const v4f*)&v[2 * D + rb];
        DOTPHASE(2)
    } else if (w == 0) {
        SJ = (double)sl_arr[0];
        const double vv0 = (double)vv_arr[0];
        AJJ = vv0 * (double)kqq_arr[0];
        trSvv = vv0;
        fa = 1.0; ga = 0.0; fb = 1.0; gb = 0.0;
        if (lane == 0) {
            out[0] = (float)((0.5 * trSvv - SJ + 0.5 * AJJ) * invl_arr[0]);
            out[SEQ] = 1.f;
            decLDS[2][0] = 1.f; decLDS[2][1] = 0.f; decLDS[2][2] = 0.f; decLDS[2][3] = 0.f;
        }
    }
    __syncthreads();

    // rounds 0..1022 (341 triples) + tail round 1023 (LAST, phase 0)
    for (int r = 0; r < 1023; r += 3) {
        ROUND(r,     0, 1, 2, false)
        ROUND(r + 1, 1, 2, 0, false)
        ROUND(r + 2, 2, 0, 1, false)
    }
    ROUND(1023, 0, 1, 2, true)

    // ---- epilogue: apply pair-1023 update (decLDS[0]) and store J ----
    if (isj) {
        J_UPDATE(0)
        float* jb = out + 2 * SEQ + (size_t)rb * D + 8 * i16;
        *(v4f*)(jb + 0)         = __builtin_shufflevector(jA0, jA1, 0, 1, 2, 3);
        *(v4f*)(jb + 4)         = __builtin_shufflevector(jA2, jA3, 0, 1, 2, 3);
        *(v4f*)(jb + D + 0)     = __builtin_shufflevector(jB0, jB1, 0, 1, 2, 3);
        *(v4f*)(jb + D + 4)     = __builtin_shufflevector(jB2, jB3, 0, 1, 2, 3);
        *(v4f*)(jb + 2 * D + 0) = __builtin_shufflevector(jC0, jC1, 0, 1, 2, 3);
        *(v4f*)(jb + 2 * D + 4) = __builtin_shufflevector(jC2, jC3, 0, 1, 2, 3);
        *(v4f*)(jb + 3 * D + 0) = __builtin_shufflevector(jD0, jD1, 0, 1, 2, 3);
        *(v4f*)(jb + 3 * D + 4) = __builtin_shufflevector(jD2, jD3, 0, 1, 2, 3);
    }
}

extern "C" void kernel_launch(void* const* d_in, const int* in_sizes, int n_in,
                              void* d_out, int out_size, void* d_ws, size_t ws_size,
                              hipStream_t stream) {
    (void)in_sizes; (void)n_in; (void)out_size; (void)ws_size;
    const float* q = (const float*)d_in[0];
    const float* k = (const float*)d_in[1];
    const float* v = (const float*)d_in[2];
    float* out = (float*)d_out;

    float* U      = (float*)d_ws;            // SEQ*D floats (1 MB)
    float* sl     = U + (size_t)SEQ * D;     // SEQ
    float* kqq    = sl + SEQ;                // SEQ
    float* vv     = kqq + SEQ;               // SEQ
    float* kq_adj = vv + SEQ;                // SEQ (legacy)
    float* vv_adj = kq_adj + SEQ;            // SEQ (legacy)
    float* kU_adj = vv_adj + SEQ;            // SEQ (legacy)
    double* invl  = (double*)(kU_adj + SEQ); // SEQ doubles
    float* kq_d   = (float*)(invl + SEQ);    // SEQ*3
    float* vv_d   = kq_d + (size_t)SEQ * 3;  // SEQ*3
    float* kU_d   = vv_d + (size_t)SEQ * 3;  // SEQ*3

    hipMemsetAsync(kq_d, 0, 3 * (size_t)SEQ * 3 * sizeof(float), stream);
    precompute_kernel<<<SEQ, 256, 0, stream>>>(q, k, v, U, sl, kqq, vv,
                                               kq_adj, vv_adj, kU_adj, invl,
                                               kq_d, vv_d, kU_d);
    scan_kernel<<<1, 1024, 0, stream>>>(q, k, v, U, sl, kqq, vv,
                                        kq_d, vv_d, kU_d, invl, out);
}

// Round 6
// 3031.810 us; speedup vs baseline: 1.7051x; 1.7051x over previous
//
#include <hip/hip_runtime.h>

#define SEQ 2048
#define D 128

typedef float v2f __attribute__((ext_vector_type(2)));
typedef float v4f __attribute__((ext_vector_type(4)));
#define LO2(v) __builtin_shufflevector(v, v, 0, 1)
#define HI2(v) __builtin_shufflevector(v, v, 2, 3)

// ---------------------------------------------------------------------------
// DPP helpers (R7/R10/R11-verified):
// ---------------------------------------------------------------------------
#define DPP_ADD(x, ctrl) \
    ((x) + __int_as_float(__builtin_amdgcn_update_dpp(0, __float_as_int(x), (ctrl), 0xf, 0xf, true)))
#define COMBINE8(x) do { x = DPP_ADD(x, 0xB1); x = DPP_ADD(x, 0x4E); x = DPP_ADD(x, 0x141); } while (0)
#define TAIL3(x)    do { x = DPP_ADD(x, 0x140); x = DPP_ADD(x, 0x142); x = DPP_ADD(x, 0x143); } while (0)
#define REDUCE16(x) do { x = DPP_ADD(x, 0xB1); x = DPP_ADD(x, 0x4E); x = DPP_ADD(x, 0x141); \
                         x = DPP_ADD(x, 0x140); } while (0)

// packed-fp32 rank-1 update; uses j0..j7, k0_..k7_, vcur from enclosing scope
#define UPDATE_J(MODE, WF, WI)                                                \
    if ((MODE) == 2) {                                                        \
        const v2f vc2 = {vcur, vcur};                                         \
        j0 = vc2 * k0_; j1 = vc2 * k1_; j2 = vc2 * k2_; j3 = vc2 * k3_;       \
        j4 = vc2 * k4_; j5 = vc2 * k5_; j6 = vc2 * k6_; j7 = vc2 * k7_;       \
    } else if ((MODE) == 1) {                                                 \
        const v2f wf2 = {(WF), (WF)};                                         \
        const float wvr_ = (WI) * vcur;                                       \
        const v2f wv2 = {wvr_, wvr_};                                         \
        j0 = __builtin_elementwise_fma(j0, wf2, wv2 * k0_);                   \
        j1 = __builtin_elementwise_fma(j1, wf2, wv2 * k1_);                   \
        j2 = __builtin_elementwise_fma(j2, wf2, wv2 * k2_);                   \
        j3 = __builtin_elementwise_fma(j3, wf2, wv2 * k3_);                   \
        j4 = __builtin_elementwise_fma(j4, wf2, wv2 * k4_);                   \
        j5 = __builtin_elementwise_fma(j5, wf2, wv2 * k5_);                   \
        j6 = __builtin_elementwise_fma(j6, wf2, wv2 * k6_);                   \
        j7 = __builtin_elementwise_fma(j7, wf2, wv2 * k7_);                   \
    }

// ---------------------------------------------------------------------------
// ROUND-21: FUSED producer/consumer kernel.
//  - block 0: the R15 scan (fastest measured: 1931us) byte-identical logic,
//    plus a flag gate every 96 bodies (lookahead +99 covers stager row I+4,
//    wave0 feeds I+1, and kq_adj[I+1] which block I produces).
//  - blocks 1..SEQ: precompute for row s=blockIdx-1, spread over all 1024
//    threads (pass1 stride 1024; pass2 8-way parity), ending with
//    __threadfence() + device-scope release store of flags[s].
//  Rationale: 5 rounds of scan restructuring all failed to beat R15's
//  ~1us/step; the remaining ~480us of the 2412 total is the serialized
//  precompute launch, which this fusion hides under the scan.
// ---------------------------------------------------------------------------
__global__ __launch_bounds__(1024, 2) void fused_kernel(
    const float* __restrict__ q, const float* __restrict__ k, const float* __restrict__ v,
    float* __restrict__ U, float* __restrict__ sl_arr,
    float* __restrict__ kqq_arr, float* __restrict__ vv_arr,
    float* __restrict__ kq_adj, float* __restrict__ vv_adj,
    float* __restrict__ kU_adj, double* __restrict__ invl_arr,
    float* __restrict__ out, int* flags)
{
    const int tid  = threadIdx.x;
    const int lane = tid & 63;

    // =======================================================================
    // PRODUCER blocks: precompute row s, then release flags[s]
    // =======================================================================
    if (blockIdx.x != 0) {
        const int s = blockIdx.x - 1;

        __shared__ float ks[D];
        __shared__ float vs[D];
        __shared__ float alpha[SEQ];
        __shared__ float red[32];
        __shared__ float upart[1024];

        if (tid < D) ks[tid] = k[s * D + tid];
        else if (tid < 2 * D) vs[tid - D] = v[s * D + (tid - D)];
        __syncthreads();

        // pass 1: alpha_i = k_s.q_i, partials for kqq/sl, vv[s]
        float p_a2 = 0.f, p_ab = 0.f;
        for (int i = tid; i <= s; i += 1024) {
            const float4* qr = (const float4*)(q + (size_t)i * D);
            const float4* vr = (const float4*)(v + (size_t)i * D);
            float a = 0.f, b = 0.f;
#pragma unroll
            for (int j = 0; j < D / 4; ++j) {
                float4 q4 = qr[j];
                float4 v4 = vr[j];
                a += q4.x * ks[4 * j + 0] + q4.y * ks[4 * j + 1] + q4.z * ks[4 * j + 2] + q4.w * ks[4 * j + 3];
                b += v4.x * vs[4 * j + 0] + v4.y * vs[4 * j + 1] + v4.z * vs[4 * j + 2] + v4.w * vs[4 * j + 3];
            }
            alpha[i] = a;
            p_a2 += a * a;
            p_ab += a * b;
            if (i == s) vv_arr[s] = b;  // v_s . v_s
        }
#pragma unroll
        for (int off = 1; off < 64; off <<= 1) {
            p_a2 += __shfl_xor(p_a2, off);
            p_ab += __shfl_xor(p_ab, off);
        }
        const int wid = tid >> 6;
        if ((tid & 63) == 0) { red[wid] = p_a2; red[16 + wid] = p_ab; }
        __syncthreads();  // also makes alpha[] visible to everyone
        if (tid == 0) {
            float s1 = 0.f, s2 = 0.f;
#pragma unroll
            for (int j = 0; j < 16; ++j) { s1 += red[j]; s2 += red[16 + j]; }
            kqq_arr[s] = s1;
            sl_arr[s]  = s2;
            invl_arr[s] = 1.0 / (double)(s + 1);
        }

        // adjacency dots: wave 0 -> kq_adj[s+1], wave 1 -> vv_adj[s]
        if (tid < 64) {
            if (s + 1 < SEQ) {
                float p2 = ks[tid] * q[(size_t)(s + 1) * D + tid]
                         + ks[tid + 64] * q[(size_t)(s + 1) * D + 64 + tid];
#pragma unroll
                for (int off = 1; off < 64; off <<= 1) p2 += __shfl_xor(p2, off);
                if (tid == 0) kq_adj[s + 1] = p2;
            }
            if (s == 0 && tid == 0) { kq_adj[0] = 0.f; kU_adj[0] = 0.f; vv_adj[0] = 0.f; }
        } else if (tid < 128 && s > 0) {
            const int t2 = tid - 64;
            float p2 = vs[t2] * v[(size_t)(s - 1) * D + t2]
                     + vs[t2 + 64] * v[(size_t)(s - 1) * D + 64 + t2];
#pragma unroll
            for (int off = 1; off < 64; off <<= 1) p2 += __shfl_xor(p2, off);
            if (t2 == 0) vv_adj[s] = p2;
        }

        // pass 2: U[s][c] = sum_i q[i][c]*alpha[i], 8-way parity over h
        const int c = tid & (D - 1);
        const int h = tid >> 7;  // 0..7
        float a0 = 0.f, a1 = 0.f, a2 = 0.f, a3 = 0.f;
        int i = h;
        for (; i + 24 <= s; i += 32) {
            a0 = fmaf(q[(size_t)(i     ) * D + c], alpha[i     ], a0);
            a1 = fmaf(q[(size_t)(i +  8) * D + c], alpha[i +  8], a1);
            a2 = fmaf(q[(size_t)(i + 16) * D + c], alpha[i + 16], a2);
            a3 = fmaf(q[(size_t)(i + 24) * D + c], alpha[i + 24], a3);
        }
        for (; i <= s; i += 8) a0 = fmaf(q[(size_t)i * D + c], alpha[i], a0);
        upart[tid] = (a0 + a1) + (a2 + a3);
        __syncthreads();

        // U store + kU_adj[s] = k_{s-1}.U_s
        float kup = 0.f;
        if (tid < D) {
            float uv = 0.f;
#pragma unroll
            for (int j = 0; j < 8; ++j) uv += upart[tid + 128 * j];
            U[(size_t)s * D + tid] = uv;
            if (s > 0) kup = uv * k[(size_t)(s - 1) * D + tid];
        }
#pragma unroll
        for (int off = 1; off < 64; off <<= 1) kup += __shfl_xor(kup, off);
        if (tid == 0)  red[0] = kup;
        if (tid == 64) red[1] = kup;
        __syncthreads();
        if (s > 0 && tid == 0) kU_adj[s] = red[0] + red[1];

        // release this row to the consumer
        __syncthreads();
        __threadfence();
        if (tid == 0)
            __hip_atomic_store(&flags[s], 1, __ATOMIC_RELEASE, __HIP_MEMORY_SCOPE_AGENT);
        return;
    }

    // =======================================================================
    // CONSUMER block 0: R15 scan + row gates
    // =======================================================================
#define WAITGATE(T)                                                           \
    {                                                                         \
        int t_ = (T); if (t_ > SEQ - 1) t_ = SEQ - 1;                         \
        int i0_ = t_ - 127; if (i0_ < 0) i0_ = 0;                             \
        const int a_ = i0_ + lane; const int b_ = a_ + 64;                    \
        for (;;) {                                                            \
            int fa_ = (a_ <= t_) ? __hip_atomic_load(&flags[a_],              \
                        __ATOMIC_ACQUIRE, __HIP_MEMORY_SCOPE_AGENT) : 1;      \
            int fb_ = (b_ <= t_) ? __hip_atomic_load(&flags[b_],              \
                        __ATOMIC_ACQUIRE, __HIP_MEMORY_SCOPE_AGENT) : 1;      \
            if (__all(fa_ && fb_)) break;                                     \
            __builtin_amdgcn_s_sleep(8);                                      \
        }                                                                     \
    }

    const int w    = __builtin_amdgcn_readfirstlane(tid >> 6);  // 0..15
    const int r    = tid >> 3;        // my row 0..127
    const int cg   = tid & 7;
    const int c0s  = cg * 20;         // swizzled LDS chunk offset

    v2f j0 = {0.f, 0.f}, j1 = j0, j2 = j0, j3 = j0, j4 = j0, j5 = j0, j6 = j0, j7 = j0;

    __shared__ float ring[3][3][160];                 // [phase][q,u,k][swizzled]
    __shared__ __align__(16) float wred[3][16][4];    // [phase][wave][r1,r2,r3,r4]
    __shared__ __align__(16) float decLDS[3][4];      // [phase][wf,wi,mode,-]

    // stagers: waves 6..11 (tid 384..767) — wave0 stays staging-free
    const bool stager = (tid >= 384) && (tid < 768);
    const int  which  = (tid >> 7) - 3;    // 0:q 1:u 2:k (when stager)
    const int  sidx   = tid & 127;
    const int  widx   = ((sidx >> 4) * 20) + (sidx & 15);  // swizzled write idx

    // rows 0..99 ready before touching any produced data
    WAITGATE(99)

    // ---- prologue: stage phases 0,1; gstage holds phase-2 data ----
    // invariant: phase j holds q_{j+1}, u_{j+1}, k_j
    float gstage = 0.f;
    if (stager) {
        if (which == 0) {
            ring[0][0][widx] = q[(size_t)1 * D + sidx];
            ring[1][0][widx] = q[(size_t)2 * D + sidx];
            gstage = q[(size_t)3 * D + sidx];
        } else if (which == 1) {
            ring[0][1][widx] = U[(size_t)1 * D + sidx];
            ring[1][1][widx] = U[(size_t)2 * D + sidx];
            gstage = U[(size_t)3 * D + sidx];
        } else {
            ring[0][2][widx] = k[sidx];
            ring[1][2][widx] = k[(size_t)1 * D + sidx];
            gstage = k[(size_t)2 * D + sidx];
        }
    }
    float vcur = v[r], vnext = v[(size_t)D + r], vn2 = v[(size_t)2 * D + r];

    // dec_0 is always mode 2 (first step: J_0 = v_0 k_0^T); read at body 0
    float dwf = 0.f, dwi = 1.f;
    int dmode = 2;
    if (tid == 0) { decLDS[0][0] = 0.f; decLDS[0][1] = 1.f; decLDS[0][2] = 2.f; decLDS[0][3] = 0.f; }

    double SJ = 0.0, AJJ = 0.0, trSvv = 0.0;  // live on wave 0 only
    if (w == 0) {
        const double sl0 = (double)sl_arr[0];
        const double kq0 = (double)kqq_arr[0];
        const double vv0 = (double)vv_arr[0];
        trSvv = vv0;
        SJ  = sl0;
        AJJ = vv0 * kq0;
        if (lane == 0) {
            out[0] = (float)((0.5 * trSvv - SJ + 0.5 * AJJ) * invl_arr[0]);
            out[SEQ] = 1.f;
        }
    }
    __syncthreads();

#define STEP_BODY(I, P, PN, PW)                                               \
{                                                                             \
    float c_sl = 0.f, c_kq = 0.f, c_vv = 0.f, c_kqa = 0.f, c_vva = 0.f,       \
          c_vvp = 0.f, c_kua = 0.f;                                           \
    double c_inv = 0.0;                                                       \
    if (w == 0) {                                                             \
        c_sl  = sl_arr[(I) + 1];  c_kq  = kqq_arr[(I) + 1];                   \
        c_vv  = vv_arr[(I) + 1];  c_kqa = kq_adj[(I) + 1];                    \
        c_vva = vv_adj[(I) + 1];  c_vvp = vv_arr[(I)];                        \
        c_kua = kU_adj[(I) + 1];  c_inv = invl_arr[(I) + 1];                  \
    }                                                                         \
    const v4f Qa = ((const v4f*)&ring[P][0][c0s])[0];                         \
    const v4f Qb = ((const v4f*)&ring[P][0][c0s])[1];                         \
    const v4f Qc = ((const v4f*)&ring[P][0][c0s])[2];                         \
    const v4f Qd = ((const v4f*)&ring[P][0][c0s])[3];                         \
    const v4f Ua = ((const v4f*)&ring[P][1][c0s])[0];                         \
    const v4f Ub = ((const v4f*)&ring[P][1][c0s])[1];                         \
    const v4f Uc = ((const v4f*)&ring[P][1][c0s])[2];                         \
    const v4f Ud = ((const v4f*)&ring[P][1][c0s])[3];                         \
    const v4f Ka = ((const v4f*)&ring[P][2][c0s])[0];                         \
    const v4f Kb = ((const v4f*)&ring[P][2][c0s])[1];                         \
    const v4f Kc = ((const v4f*)&ring[P][2][c0s])[2];                         \
    const v4f Kd = ((const v4f*)&ring[P][2][c0s])[3];                         \
    const v2f k0_ = LO2(Ka), k1_ = HI2(Ka), k2_ = LO2(Kb), k3_ = HI2(Kb);     \
    const v2f k4_ = LO2(Kc), k5_ = HI2(Kc), k6_ = LO2(Kd), k7_ = HI2(Kd);     \
    v2f aq0 = {0.f, 0.f}, aq1 = aq0, aq2 = aq0, aq3 = aq0;                    \
    aq0 = __builtin_elementwise_fma(j0, LO2(Qa), aq0);                        \
    aq1 = __builtin_elementwise_fma(j1, HI2(Qa), aq1);                        \
    aq2 = __builtin_elementwise_fma(j2, LO2(Qb), aq2);                        \
    aq3 = __builtin_elementwise_fma(j3, HI2(Qb), aq3);                        \
    aq0 = __builtin_elementwise_fma(j4, LO2(Qc), aq0);                        \
    aq1 = __builtin_elementwise_fma(j5, HI2(Qc), aq1);                        \
    aq2 = __builtin_elementwise_fma(j6, LO2(Qd), aq2);                        \
    aq3 = __builtin_elementwise_fma(j7, HI2(Qd), aq3);                        \
    const v2f sq_ = (aq0 + aq1) + (aq2 + aq3);                                \
    float Yq = sq_.x + sq_.y;                                                 \
    v2f au0 = {0.f, 0.f}, au1 = au0, au2 = au0, au3 = au0;                    \
    au0 = __builtin_elementwise_fma(j0, LO2(Ua), au0);                        \
    au1 = __builtin_elementwise_fma(j1, HI2(Ua), au1);                        \
    au2 = __builtin_elementwise_fma(j2, LO2(Ub), au2);                        \
    au3 = __builtin_elementwise_fma(j3, HI2(Ub), au3);                        \
    au0 = __builtin_elementwise_fma(j4, LO2(Uc), au0);                        \
    au1 = __builtin_elementwise_fma(j5, HI2(Uc), au1);                        \
    au2 = __builtin_elementwise_fma(j6, LO2(Ud), au2);                        \
    au3 = __builtin_elementwise_fma(j7, HI2(Ud), au3);                        \
    const v2f su_ = (au0 + au1) + (au2 + au3);                                \
    float Yw = su_.x + su_.y;                                                 \
    COMBINE8(Yq);                                                             \
    COMBINE8(Yw);                                                             \
    float z1 = vnext * Yq;                                                    \
    float z2 = Yq * Yq;                                                       \
    float z3 = vcur  * Yq;                                                    \
    float z4 = vnext * Yw;                                                    \
    TAIL3(z1);                                                                \
    TAIL3(z2);                                                                \
    TAIL3(z3);                                                                \
    TAIL3(z4);                                                                \
    if (lane == 63) *(float4*)&wred[P][w][0] = make_float4(z1, z2, z3, z4);   \
    __syncthreads();                                                          \
    if (stager) {                                                             \
        ring[PW][which][widx] = gstage;                                       \
        const int tq_ = ((I) + 4 < SEQ) ? (I) + 4 : SEQ - 1;                  \
        const int tk_ = ((I) + 3 < SEQ) ? (I) + 3 : SEQ - 1;                  \
        gstage = (which == 0) ? q[(size_t)tq_ * D + sidx]                     \
               : (which == 1) ? U[(size_t)tq_ * D + sidx]                     \
                              : k[(size_t)tk_ * D + sidx];                    \
    }                                                                         \
    const int tv_ = ((I) + 3 < SEQ) ? (I) + 3 : SEQ - 1;                      \
    const float vnew_ = v[(size_t)tv_ * D + r];                               \
    if (w == 0) {                                                             \
        float4 ww = *(const float4*)&wred[P][lane & 15][0];                   \
        const float odwf = dwf, odwi = dwi;                                   \
        const int   odmode = dmode;                                           \
        UPDATE_J(odmode, odwf, odwi)                                          \
        REDUCE16(ww.x);                                                       \
        REDUCE16(ww.y);                                                       \
        REDUCE16(ww.z);                                                       \
        REDUCE16(ww.w);                                                       \
        double a_, b_;                                                        \
        if (odmode == 2)      { a_ = 0.0; b_ = 1.0; }                         \
        else if (odmode == 1) { a_ = (double)odwf; b_ = (double)odwi; }       \
        else                  { a_ = 1.0; b_ = 0.0; }                         \
        const double kqa = (double)c_kqa, vva = (double)c_vva;                \
        const double vvp = (double)c_vvp, kua = (double)c_kua;                \
        const double r1 = (double)ww.x * 0.125, r2 = (double)ww.y * 0.125;    \
        const double r3 = (double)ww.z * 0.125, r4 = (double)ww.w * 0.125;    \
        const double Jqv  = a_ * r1 + b_ * (kqa * vva);                       \
        const double Jq2  = a_ * a_ * r2 + 2.0 * a_ * b_ * kqa * r3          \
                          + b_ * b_ * kqa * kqa * vvp;                        \
        const double AJl_ = a_ * r4 + b_ * kua * vva;                         \
        trSvv += (double)c_vv;                                                \
        SJ    += Jqv;                                                         \
        AJJ   += Jq2;                                                         \
        const double s_l  = (double)c_sl;                                     \
        const double A_ll = (double)c_vv * (double)c_kq;                      \
        const double AJJ_s  = (AJJ == 0.0)  ? 1.0 : AJJ;                      \
        const double A_ll_s = (A_ll == 0.0) ? 1.0 : A_ll;                     \
        const double denom   = AJJ * A_ll - AJl_ * AJl_;                      \
        const double denom_s = (denom == 0.0) ? 1.0 : denom;                  \
        const double rden = 1.0 / denom_s;                                    \
        const double wf = (A_ll * SJ - AJl_ * s_l) * rden;                    \
        const double wi = (AJJ * s_l - AJl_ * SJ) * rden;                     \
        double wf_c, wi_c;                                                    \
        if (wi <= 0.0)      { wf_c = SJ / AJJ_s;  wi_c = 0.0; }               \
        else if (wf <= 0.0) { wf_c = 0.0;         wi_c = s_l / A_ll_s; }      \
        else                { wf_c = wf;          wi_c = wi; }                \
        const bool do_update = (s_l * AJJ_s - AJl_ * SJ) > 0.0;               \
        int mode;                                                             \
        if (do_update) {                                                      \
            mode = 1;                                                         \
            const double nSJ = wf_c * SJ + wi_c * s_l;                        \
            AJJ = wf_c * wf_c * AJJ + 2.0 * wf_c * wi_c * AJl_                \
                + wi_c * wi_c * A_ll;                                         \
            SJ = nSJ;                                                         \
        } else {                                                              \
            mode = 0;                                                         \
        }                                                                     \
        dwf = (float)wf_c; dwi = (float)wi_c; dmode = mode;                   \
        if (lane == 0) {                                                      \
            out[(I) + 1] = (float)((0.5 * trSvv - SJ + 0.5 * AJJ) * c_inv);   \
            out[SEQ + (I) + 1] = mode ? 1.f : 0.f;                            \
            *(float4*)&decLDS[PN][0] = make_float4(dwf, dwi, (float)mode, 0.f);\
        }                                                                     \
    } else {                                                                  \
        const float4 df = *(const float4*)&decLDS[P][0];                      \
        dwf = df.x; dwi = df.y; dmode = (int)df.z;                            \
        UPDATE_J(dmode, dwf, dwi)                                             \
    }                                                                         \
    vcur = vnext; vnext = vn2; vn2 = vnew_;                                   \
}

    // bodies I = 0..SEQ-2 (2047 of them): 682 x3-unrolled + 1 tail (2046%3==0)
    for (int i = 0; i + 2 < SEQ - 1; i += 3) {
        if (i && (i % 96) == 0) WAITGATE(i + 99)
        STEP_BODY(i,     0, 1, 2)
        STEP_BODY(i + 1, 1, 2, 0)
        STEP_BODY(i + 2, 2, 0, 1)
    }
    STEP_BODY(SEQ - 2, 0, 1, 2)
#undef STEP_BODY
#undef WAITGATE

    // ---- epilogue: apply final update (dec_{SEQ-1}, phase (SEQ-1)%3 = 1) ----
    __syncthreads();  // make wave0's decLDS[1] write visible
    {
        const float4 df = *(const float4*)&decLDS[1][0];
        const float fwf = df.x, fwi = df.y;
        const int   fmode = (int)df.z;
        const v4f Ka = ((const v4f*)&ring[1][2][c0s])[0];
        const v4f Kb = ((const v4f*)&ring[1][2][c0s])[1];
        const v4f Kc = ((const v4f*)&ring[1][2][c0s])[2];
        const v4f Kd = ((const v4f*)&ring[1][2][c0s])[3];
        const v2f k0_ = LO2(Ka), k1_ = HI2(Ka), k2_ = LO2(Kb), k3_ = HI2(Kb);
        const v2f k4_ = LO2(Kc), k5_ = HI2(Kc), k6_ = LO2(Kd), k7_ = HI2(Kd);
        UPDATE_J(fmode, fwf, fwi)
        float* jbase = out + 2 * SEQ + (size_t)r * D + cg * 16;
        *(v4f*)(jbase + 0)  = __builtin_shufflevector(j0, j1, 0, 1, 2, 3);
        *(v4f*)(jbase + 4)  = __builtin_shufflevector(j2, j3, 0, 1, 2, 3);
        *(v4f*)(jbase + 8)  = __builtin_shufflevector(j4, j5, 0, 1, 2, 3);
        *(v4f*)(jbase + 12) = __builtin_shufflevector(j6, j7, 0, 1, 2, 3);
    }
}

extern "C" void kernel_launch(void* const* d_in, const int* in_sizes, int n_in,
                              void* d_out, int out_size, void* d_ws, size_t ws_size,
                              hipStream_t stream) {
    (void)in_sizes; (void)n_in; (void)out_size; (void)ws_size;
    const float* q = (const float*)d_in[0];
    const float* k = (const float*)d_in[1];
    const float* v = (const float*)d_in[2];
    float* out = (float*)d_out;

    float* U      = (float*)d_ws;            // SEQ*D floats (1 MB)
    float* sl     = U + (size_t)SEQ * D;     // SEQ
    float* kqq    = sl + SEQ;                // SEQ
    float* vv     = kqq + SEQ;               // SEQ
    float* kq_adj = vv + SEQ;                // SEQ
    float* vv_adj = kq_adj + SEQ;            // SEQ
    float* kU_adj = vv_adj + SEQ;            // SEQ
    double* invl  = (double*)(kU_adj + SEQ); // SEQ doubles (8B-aligned)
    int*    flags = (int*)(invl + SEQ);      // SEQ ints (row-ready flags)

    hipMemsetAsync(flags, 0, SEQ * sizeof(int), stream);
    fused_kernel<<<SEQ + 1, 1024, 0, stream>>>(q, k, v, U, sl, kqq, vv,
                                               kq_adj, vv_adj, kU_adj, invl,
                                               out, flags);
}

// Round 7
// 2548.715 us; speedup vs baseline: 2.0283x; 1.1895x over previous
//
#include <hip/hip_runtime.h>

#define SEQ 2048
#define D 128

typedef float v2f __attribute__((ext_vector_type(2)));
typedef float v4f __attribute__((ext_vector_type(4)));
#define LO2(v) __builtin_shufflevector(v, v, 0, 1)
#define HI2(v) __builtin_shufflevector(v, v, 2, 3)

// ---------------------------------------------------------------------------
// DPP helpers (R7/R10/R11-verified):
// ---------------------------------------------------------------------------
#define DPP_ADD(x, ctrl) \
    ((x) + __int_as_float(__builtin_amdgcn_update_dpp(0, __float_as_int(x), (ctrl), 0xf, 0xf, true)))
#define COMBINE8(x) do { x = DPP_ADD(x, 0xB1); x = DPP_ADD(x, 0x4E); x = DPP_ADD(x, 0x141); } while (0)
#define TAIL3(x)    do { x = DPP_ADD(x, 0x140); x = DPP_ADD(x, 0x142); x = DPP_ADD(x, 0x143); } while (0)
#define REDUCE16(x) do { x = DPP_ADD(x, 0xB1); x = DPP_ADD(x, 0x4E); x = DPP_ADD(x, 0x141); \
                         x = DPP_ADD(x, 0x140); } while (0)

// packed-fp32 rank-1 update; uses j0..j7, k0_..k7_, vcur from enclosing scope
#define UPDATE_J(MODE, WF, WI)                                                \
    if ((MODE) == 2) {                                                        \
        const v2f vc2 = {vcur, vcur};                                         \
        j0 = vc2 * k0_; j1 = vc2 * k1_; j2 = vc2 * k2_; j3 = vc2 * k3_;       \
        j4 = vc2 * k4_; j5 = vc2 * k5_; j6 = vc2 * k6_; j7 = vc2 * k7_;       \
    } else if ((MODE) == 1) {                                                 \
        const v2f wf2 = {(WF), (WF)};                                         \
        const float wvr_ = (WI) * vcur;                                       \
        const v2f wv2 = {wvr_, wvr_};                                         \
        j0 = __builtin_elementwise_fma(j0, wf2, wv2 * k0_);                   \
        j1 = __builtin_elementwise_fma(j1, wf2, wv2 * k1_);                   \
        j2 = __builtin_elementwise_fma(j2, wf2, wv2 * k2_);                   \
        j3 = __builtin_elementwise_fma(j3, wf2, wv2 * k3_);                   \
        j4 = __builtin_elementwise_fma(j4, wf2, wv2 * k4_);                   \
        j5 = __builtin_elementwise_fma(j5, wf2, wv2 * k5_);                   \
        j6 = __builtin_elementwise_fma(j6, wf2, wv2 * k6_);                   \
        j7 = __builtin_elementwise_fma(j7, wf2, wv2 * k7_);                   \
    }

// ---------------------------------------------------------------------------
// ROUND-22: fused producer/consumer, fence-storm + CU-sharing fixed.
//  R21 counters: FETCH 1.03GB / WRITE 1.38GB (inputs are 4MB!) -- 2048
//  per-block device-scope release fences each force an L2 writeback
//  (cross-XCD visibility), flushing the producers' shared L2s continuously.
//  Also the "isolation pad" was 32KB not >80KB, so the scan SHARED its CU.
//  Fixes:
//   * 256 producer blocks x 8 consecutive rows, ONE threadfence + ONE
//     release-flag per block (8x fewer L2 writebacks).
//   * LDS padded to 87.6KB -> 1 block/CU guaranteed; scan CU is private.
//   * scan = byte-identical R15 (fastest measured), gating on 256 flags.
// ---------------------------------------------------------------------------
__global__ __launch_bounds__(1024, 4) void fused_kernel(
    const float* __restrict__ q, const float* __restrict__ k, const float* __restrict__ v,
    float* __restrict__ U, float* __restrict__ sl_arr,
    float* __restrict__ kqq_arr, float* __restrict__ vv_arr,
    float* __restrict__ kq_adj, float* __restrict__ vv_adj,
    float* __restrict__ kU_adj, double* __restrict__ invl_arr,
    float* __restrict__ out, int* flags)
{
    const int tid  = threadIdx.x;
    const int lane = tid & 63;

    __shared__ double lpad[8448];   // 67.6KB pad -> total LDS ~87.6KB -> 1 block/CU
    if (tid == 0) lpad[0] = (double)blockIdx.x;   // keep allocation live

    // =======================================================================
    // PRODUCER blocks: precompute rows 8b..8b+7, then ONE release of flags[b]
    // =======================================================================
    if (blockIdx.x != 0) {
        const int b = blockIdx.x - 1;

        __shared__ float ks[D];
        __shared__ float vs[D];
        __shared__ float alpha[SEQ];
        __shared__ float red[32];
        __shared__ float upart[1024];

        for (int rr = 0; rr < 8; ++rr) {
            const int s = b * 8 + rr;
            __syncthreads();   // protect ks/vs/alpha reuse across rows

            if (tid < D) ks[tid] = k[s * D + tid];
            else if (tid < 2 * D) vs[tid - D] = v[s * D + (tid - D)];
            __syncthreads();

            // pass 1: alpha_i = k_s.q_i, partials for kqq/sl, vv[s]
            float p_a2 = 0.f, p_ab = 0.f;
            for (int i = tid; i <= s; i += 1024) {
                const float4* qr = (const float4*)(q + (size_t)i * D);
                const float4* vr = (const float4*)(v + (size_t)i * D);
                float a = 0.f, bb = 0.f;
#pragma unroll
                for (int j = 0; j < D / 4; ++j) {
                    float4 q4 = qr[j];
                    float4 v4 = vr[j];
                    a += q4.x * ks[4 * j + 0] + q4.y * ks[4 * j + 1] + q4.z * ks[4 * j + 2] + q4.w * ks[4 * j + 3];
                    bb += v4.x * vs[4 * j + 0] + v4.y * vs[4 * j + 1] + v4.z * vs[4 * j + 2] + v4.w * vs[4 * j + 3];
                }
                alpha[i] = a;
                p_a2 += a * a;
                p_ab += a * bb;
                if (i == s) vv_arr[s] = bb;  // v_s . v_s
            }
#pragma unroll
            for (int off = 1; off < 64; off <<= 1) {
                p_a2 += __shfl_xor(p_a2, off);
                p_ab += __shfl_xor(p_ab, off);
            }
            const int wid = tid >> 6;
            if ((tid & 63) == 0) { red[wid] = p_a2; red[16 + wid] = p_ab; }
            __syncthreads();  // also makes alpha[] visible to everyone
            if (tid == 0) {
                float s1 = 0.f, s2 = 0.f;
#pragma unroll
                for (int j = 0; j < 16; ++j) { s1 += red[j]; s2 += red[16 + j]; }
                kqq_arr[s] = s1;
                sl_arr[s]  = s2;
                invl_arr[s] = 1.0 / (double)(s + 1);
            }

            // adjacency dots: wave 0 -> kq_adj[s+1], wave 1 -> vv_adj[s]
            if (tid < 64) {
                if (s + 1 < SEQ) {
                    float p2 = ks[tid] * q[(size_t)(s + 1) * D + tid]
                             + ks[tid + 64] * q[(size_t)(s + 1) * D + 64 + tid];
#pragma unroll
                    for (int off = 1; off < 64; off <<= 1) p2 += __shfl_xor(p2, off);
                    if (tid == 0) kq_adj[s + 1] = p2;
                }
                if (s == 0 && tid == 0) { kq_adj[0] = 0.f; kU_adj[0] = 0.f; vv_adj[0] = 0.f; }
            } else if (tid < 128 && s > 0) {
                const int t2 = tid - 64;
                float p2 = vs[t2] * v[(size_t)(s - 1) * D + t2]
                         + vs[t2 + 64] * v[(size_t)(s - 1) * D + 64 + t2];
#pragma unroll
                for (int off = 1; off < 64; off <<= 1) p2 += __shfl_xor(p2, off);
                if (t2 == 0) vv_adj[s] = p2;
            }

            // pass 2: U[s][c] = sum_i q[i][c]*alpha[i], 8-way parity over h
            const int c = tid & (D - 1);
            const int h = tid >> 7;  // 0..7
            float a0 = 0.f, a1 = 0.f, a2 = 0.f, a3 = 0.f;
            int i = h;
            for (; i + 24 <= s; i += 32) {
                a0 = fmaf(q[(size_t)(i     ) * D + c], alpha[i     ], a0);
                a1 = fmaf(q[(size_t)(i +  8) * D + c], alpha[i +  8], a1);
                a2 = fmaf(q[(size_t)(i + 16) * D + c], alpha[i + 16], a2);
                a3 = fmaf(q[(size_t)(i + 24) * D + c], alpha[i + 24], a3);
            }
            for (; i <= s; i += 8) a0 = fmaf(q[(size_t)i * D + c], alpha[i], a0);
            upart[tid] = (a0 + a1) + (a2 + a3);
            __syncthreads();

            // U store + kU_adj[s] = k_{s-1}.U_s
            float kup = 0.f;
            if (tid < D) {
                float uv = 0.f;
#pragma unroll
                for (int j = 0; j < 8; ++j) uv += upart[tid + 128 * j];
                U[(size_t)s * D + tid] = uv;
                if (s > 0) kup = uv * k[(size_t)(s - 1) * D + tid];
            }
#pragma unroll
            for (int off = 1; off < 64; off <<= 1) kup += __shfl_xor(kup, off);
            if (tid == 0)  red[0] = kup;
            if (tid == 64) red[1] = kup;
            __syncthreads();
            if (s > 0 && tid == 0) kU_adj[s] = red[0] + red[1];
        }

        // release all 8 rows with ONE device-scope fence + flag
        __syncthreads();
        __threadfence();
        if (tid == 0)
            __hip_atomic_store(&flags[b], 1, __ATOMIC_RELEASE, __HIP_MEMORY_SCOPE_AGENT);
        return;
    }

    // =======================================================================
    // CONSUMER block 0: R15 scan + block-flag gates
    // =======================================================================
#define WAITGATE(T)                                                           \
    {                                                                         \
        int t_ = (T); if (t_ > SEQ - 1) t_ = SEQ - 1;                         \
        const int fb_ = t_ >> 3;   /* need flags[0..fb_] */                   \
        for (;;) {                                                            \
            int ok_ = 1;                                                      \
            _Pragma("unroll")                                                 \
            for (int jj_ = 0; jj_ < 4; ++jj_) {                               \
                const int fi_ = lane + 64 * jj_;                              \
                if (fi_ <= fb_)                                               \
                    ok_ &= __hip_atomic_load(&flags[fi_],                     \
                             __ATOMIC_ACQUIRE, __HIP_MEMORY_SCOPE_AGENT);     \
            }                                                                 \
            if (__all(ok_)) break;                                            \
            __builtin_amdgcn_s_sleep(8);                                      \
        }                                                                     \
    }

    const int w    = __builtin_amdgcn_readfirstlane(tid >> 6);  // 0..15
    const int r    = tid >> 3;        // my row 0..127
    const int cg   = tid & 7;
    const int c0s  = cg * 20;         // swizzled LDS chunk offset

    v2f j0 = {0.f, 0.f}, j1 = j0, j2 = j0, j3 = j0, j4 = j0, j5 = j0, j6 = j0, j7 = j0;

    __shared__ float ring[3][3][160];                 // [phase][q,u,k][swizzled]
    __shared__ __align__(16) float wred[3][16][4];    // [phase][wave][r1,r2,r3,r4]
    __shared__ __align__(16) float decLDS[3][4];      // [phase][wf,wi,mode,-]

    // stagers: waves 6..11 (tid 384..767) — wave0 stays staging-free
    const bool stager = (tid >= 384) && (tid < 768);
    const int  which  = (tid >> 7) - 3;    // 0:q 1:u 2:k (when stager)
    const int  sidx   = tid & 127;
    const int  widx   = ((sidx >> 4) * 20) + (sidx & 15);  // swizzled write idx

    // rows 0..99 ready before touching any produced data
    WAITGATE(99)

    // ---- prologue: stage phases 0,1; gstage holds phase-2 data ----
    // invariant: phase j holds q_{j+1}, u_{j+1}, k_j
    float gstage = 0.f;
    if (stager) {
        if (which == 0) {
            ring[0][0][widx] = q[(size_t)1 * D + sidx];
            ring[1][0][widx] = q[(size_t)2 * D + sidx];
            gstage = q[(size_t)3 * D + sidx];
        } else if (which == 1) {
            ring[0][1][widx] = U[(size_t)1 * D + sidx];
            ring[1][1][widx] = U[(size_t)2 * D + sidx];
            gstage = U[(size_t)3 * D + sidx];
        } else {
            ring[0][2][widx] = k[sidx];
            ring[1][2][widx] = k[(size_t)1 * D + sidx];
            gstage = k[(size_t)2 * D + sidx];
        }
    }
    float vcur = v[r], vnext = v[(size_t)D + r], vn2 = v[(size_t)2 * D + r];

    // dec_0 is always mode 2 (first step: J_0 = v_0 k_0^T); read at body 0
    float dwf = 0.f, dwi = 1.f;
    int dmode = 2;
    if (tid == 0) { decLDS[0][0] = 0.f; decLDS[0][1] = 1.f; decLDS[0][2] = 2.f; decLDS[0][3] = 0.f; }

    double SJ = 0.0, AJJ = 0.0, trSvv = 0.0;  // live on wave 0 only
    if (w == 0) {
        const double sl0 = (double)sl_arr[0];
        const double kq0 = (double)kqq_arr[0];
        const double vv0 = (double)vv_arr[0];
        trSvv = vv0;
        SJ  = sl0;
        AJJ = vv0 * kq0;
        if (lane == 0) {
            out[0] = (float)((0.5 * trSvv - SJ + 0.5 * AJJ) * invl_arr[0]);
            out[SEQ] = 1.f;
        }
    }
    __syncthreads();

#define STEP_BODY(I, P, PN, PW)                                               \
{                                                                             \
    float c_sl = 0.f, c_kq = 0.f, c_vv = 0.f, c_kqa = 0.f, c_vva = 0.f,       \
          c_vvp = 0.f, c_kua = 0.f;                                           \
    double c_inv = 0.0;                                                       \
    if (w == 0) {                                                             \
        c_sl  = sl_arr[(I) + 1];  c_kq  = kqq_arr[(I) + 1];                   \
        c_vv  = vv_arr[(I) + 1];  c_kqa = kq_adj[(I) + 1];                    \
        c_vva = vv_adj[(I) + 1];  c_vvp = vv_arr[(I)];                        \
        c_kua = kU_adj[(I) + 1];  c_inv = invl_arr[(I) + 1];                  \
    }                                                                         \
    const v4f Qa = ((const v4f*)&ring[P][0][c0s])[0];                         \
    const v4f Qb = ((const v4f*)&ring[P][0][c0s])[1];                         \
    const v4f Qc = ((const v4f*)&ring[P][0][c0s])[2];                         \
    const v4f Qd = ((const v4f*)&ring[P][0][c0s])[3];                         \
    const v4f Ua = ((const v4f*)&ring[P][1][c0s])[0];                         \
    const v4f Ub = ((const v4f*)&ring[P][1][c0s])[1];                         \
    const v4f Uc = ((const v4f*)&ring[P][1][c0s])[2];                         \
    const v4f Ud = ((const v4f*)&ring[P][1][c0s])[3];                         \
    const v4f Ka = ((const v4f*)&ring[P][2][c0s])[0];                         \
    const v4f Kb = ((const v4f*)&ring[P][2][c0s])[1];                         \
    const v4f Kc = ((const v4f*)&ring[P][2][c0s])[2];                         \
    const v4f Kd = ((const v4f*)&ring[P][2][c0s])[3];                         \
    const v2f k0_ = LO2(Ka), k1_ = HI2(Ka), k2_ = LO2(Kb), k3_ = HI2(Kb);     \
    const v2f k4_ = LO2(Kc), k5_ = HI2(Kc), k6_ = LO2(Kd), k7_ = HI2(Kd);     \
    v2f aq0 = {0.f, 0.f}, aq1 = aq0, aq2 = aq0, aq3 = aq0;                    \
    aq0 = __builtin_elementwise_fma(j0, LO2(Qa), aq0);                        \
    aq1 = __builtin_elementwise_fma(j1, HI2(Qa), aq1);                        \
    aq2 = __builtin_elementwise_fma(j2, LO2(Qb), aq2);                        \
    aq3 = __builtin_elementwise_fma(j3, HI2(Qb), aq3);                        \
    aq0 = __builtin_elementwise_fma(j4, LO2(Qc), aq0);                        \
    aq1 = __builtin_elementwise_fma(j5, HI2(Qc), aq1);                        \
    aq2 = __builtin_elementwise_fma(j6, LO2(Qd), aq2);                        \
    aq3 = __builtin_elementwise_fma(j7, HI2(Qd), aq3);                        \
    const v2f sq_ = (aq0 + aq1) + (aq2 + aq3);                                \
    float Yq = sq_.x + sq_.y;                                                 \
    v2f au0 = {0.f, 0.f}, au1 = au0, au2 = au0, au3 = au0;                    \
    au0 = __builtin_elementwise_fma(j0, LO2(Ua), au0);                        \
    au1 = __builtin_elementwise_fma(j1, HI2(Ua), au1);                        \
    au2 = __builtin_elementwise_fma(j2, LO2(Ub), au2);                        \
    au3 = __builtin_elementwise_fma(j3, HI2(Ub), au3);                        \
    au0 = __builtin_elementwise_fma(j4, LO2(Uc), au0);                        \
    au1 = __builtin_elementwise_fma(j5, HI2(Uc), au1);                        \
    au2 = __builtin_elementwise_fma(j6, LO2(Ud), au2);                        \
    au3 = __builtin_elementwise_fma(j7, HI2(Ud), au3);                        \
    const v2f su_ = (au0 + au1) + (au2 + au3);                                \
    float Yw = su_.x + su_.y;                                                 \
    COMBINE8(Yq);                                                             \
    COMBINE8(Yw);                                                             \
    float z1 = vnext * Yq;                                                    \
    float z2 = Yq * Yq;                                                       \
    float z3 = vcur  * Yq;                                                    \
    float z4 = vnext * Yw;                                                    \
    TAIL3(z1);                                                                \
    TAIL3(z2);                                                                \
    TAIL3(z3);                                                                \
    TAIL3(z4);                                                                \
    if (lane == 63) *(float4*)&wred[P][w][0] = make_float4(z1, z2, z3, z4);   \
    __syncthreads();                                                          \
    if (stager) {                                                             \
        ring[PW][which][widx] = gstage;                                       \
        const int tq_ = ((I) + 4 < SEQ) ? (I) + 4 : SEQ - 1;                  \
        const int tk_ = ((I) + 3 < SEQ) ? (I) + 3 : SEQ - 1;                  \
        gstage = (which == 0) ? q[(size_t)tq_ * D + sidx]                     \
               : (which == 1) ? U[(size_t)tq_ * D + sidx]                     \
                              : k[(size_t)tk_ * D + sidx];                    \
    }                                                                         \
    const int tv_ = ((I) + 3 < SEQ) ? (I) + 3 : SEQ - 1;                      \
    const float vnew_ = v[(size_t)tv_ * D + r];                               \
    if (w == 0) {                                                             \
        float4 ww = *(const float4*)&wred[P][lane & 15][0];                   \
        const float odwf = dwf, odwi = dwi;                                   \
        const int   odmode = dmode;                                           \
        UPDATE_J(odmode, odwf, odwi)                                          \
        REDUCE16(ww.x);                                                       \
        REDUCE16(ww.y);                                                       \
        REDUCE16(ww.z);                                                       \
        REDUCE16(ww.w);                                                       \
        double a_, b_;                                                        \
        if (odmode == 2)      { a_ = 0.0; b_ = 1.0; }                         \
        else if (odmode == 1) { a_ = (double)odwf; b_ = (double)odwi; }       \
        else                  { a_ = 1.0; b_ = 0.0; }                         \
        const double kqa = (double)c_kqa, vva = (double)c_vva;                \
        const double vvp = (double)c_vvp, kua = (double)c_kua;                \
        const double r1 = (double)ww.x * 0.125, r2 = (double)ww.y * 0.125;    \
        const double r3 = (double)ww.z * 0.125, r4 = (double)ww.w * 0.125;    \
        const double Jqv  = a_ * r1 + b_ * (kqa * vva);                       \
        const double Jq2  = a_ * a_ * r2 + 2.0 * a_ * b_ * kqa * r3          \
                          + b_ * b_ * kqa * kqa * vvp;                        \
        const double AJl_ = a_ * r4 + b_ * kua * vva;                         \
        trSvv += (double)c_vv;                                                \
        SJ    += Jqv;                                                         \
        AJJ   += Jq2;                                                         \
        const double s_l  = (double)c_sl;                                     \
        const double A_ll = (double)c_vv * (double)c_kq;                      \
        const double AJJ_s  = (AJJ == 0.0)  ? 1.0 : AJJ;                      \
        const double A_ll_s = (A_ll == 0.0) ? 1.0 : A_ll;                     \
        const double denom   = AJJ * A_ll - AJl_ * AJl_;                      \
        const double denom_s = (denom == 0.0) ? 1.0 : denom;                  \
        const double rden = 1.0 / denom_s;                                    \
        const double wf = (A_ll * SJ - AJl_ * s_l) * rden;                    \
        const double wi = (AJJ * s_l - AJl_ * SJ) * rden;                     \
        double wf_c, wi_c;                                                    \
        if (wi <= 0.0)      { wf_c = SJ / AJJ_s;  wi_c = 0.0; }               \
        else if (wf <= 0.0) { wf_c = 0.0;         wi_c = s_l / A_ll_s; }      \
        else                { wf_c = wf;          wi_c = wi; }                \
        const bool do_update = (s_l * AJJ_s - AJl_ * SJ) > 0.0;               \
        int mode;                                                             \
        if (do_update) {                                                      \
            mode = 1;                                                         \
            const double nSJ = wf_c * SJ + wi_c * s_l;                        \
            AJJ = wf_c * wf_c * AJJ + 2.0 * wf_c * wi_c * AJl_                \
                + wi_c * wi_c * A_ll;                                         \
            SJ = nSJ;                                                         \
        } else {                                                              \
            mode = 0;                                                         \
        }                                                                     \
        dwf = (float)wf_c; dwi = (float)wi_c; dmode = mode;                   \
        if (lane == 0) {                                                      \
            out[(I) + 1] = (float)((0.5 * trSvv - SJ + 0.5 * AJJ) * c_inv);   \
            out[SEQ + (I) + 1] = mode ? 1.f : 0.f;                            \
            *(float4*)&decLDS[PN][0] = make_float4(dwf, dwi, (float)mode, 0.f);\
        }                                                                     \
    } else {                                                                  \
        const float4 df = *(const float4*)&decLDS[P][0];                      \
        dwf = df.x; dwi = df.y; dmode = (int)df.z;                            \
        UPDATE_J(dmode, dwf, dwi)                                             \
    }                                                                         \
    vcur = vnext; vnext = vn2; vn2 = vnew_;                                   \
}

    // bodies I = 0..SEQ-2 (2047 of them): 682 x3-unrolled + 1 tail (2046%3==0)
    for (int i = 0; i + 2 < SEQ - 1; i += 3) {
        if (i && (i % 96) == 0) WAITGATE(i + 99)
        STEP_BODY(i,     0, 1, 2)
        STEP_BODY(i + 1, 1, 2, 0)
        STEP_BODY(i + 2, 2, 0, 1)
    }
    STEP_BODY(SEQ - 2, 0, 1, 2)
#undef STEP_BODY
#undef WAITGATE

    // ---- epilogue: apply final update (dec_{SEQ-1}, phase (SEQ-1)%3 = 1) ----
    __syncthreads();  // make wave0's decLDS[1] write visible
    {
        const float4 df = *(const float4*)&decLDS[1][0];
        const float fwf = df.x, fwi = df.y;
        const int   fmode = (int)df.z;
        const v4f Ka = ((const v4f*)&ring[1][2][c0s])[0];
        const v4f Kb = ((const v4f*)&ring[1][2][c0s])[1];
        const v4f Kc = ((const v4f*)&ring[1][2][c0s])[2];
        const v4f Kd = ((const v4f*)&ring[1][2][c0s])[3];
        const v2f k0_ = LO2(Ka), k1_ = HI2(Ka), k2_ = LO2(Kb), k3_ = HI2(Kb);
        const v2f k4_ = LO2(Kc), k5_ = HI2(Kc), k6_ = LO2(Kd), k7_ = HI2(Kd);
        UPDATE_J(fmode, fwf, fwi)
        float* jbase = out + 2 * SEQ + (size_t)r * D + cg * 16;
        *(v4f*)(jbase + 0)  = __builtin_shufflevector(j0, j1, 0, 1, 2, 3);
        *(v4f*)(jbase + 4)  = __builtin_shufflevector(j2, j3, 0, 1, 2, 3);
        *(v4f*)(jbase + 8)  = __builtin_shufflevector(j4, j5, 0, 1, 2, 3);
        *(v4f*)(jbase + 12) = __builtin_shufflevector(j6, j7, 0, 1, 2, 3);
    }
}

extern "C" void kernel_launch(void* const* d_in, const int* in_sizes, int n_in,
                              void* d_out, int out_size, void* d_ws, size_t ws_size,
                              hipStream_t stream) {
    (void)in_sizes; (void)n_in; (void)out_size; (void)ws_size;
    const float* q = (const float*)d_in[0];
    const float* k = (const float*)d_in[1];
    const float* v = (const float*)d_in[2];
    float* out = (float*)d_out;

    float* U      = (float*)d_ws;            // SEQ*D floats (1 MB)
    float* sl     = U + (size_t)SEQ * D;     // SEQ
    float* kqq    = sl + SEQ;                // SEQ
    float* vv     = kqq + SEQ;               // SEQ
    float* kq_adj = vv + SEQ;                // SEQ
    float* vv_adj = kq_adj + SEQ;            // SEQ
    float* kU_adj = vv_adj + SEQ;            // SEQ
    double* invl  = (double*)(kU_adj + SEQ); // SEQ doubles (8B-aligned)
    int*    flags = (int*)(invl + SEQ);      // 256 ints (block-ready flags)

    hipMemsetAsync(flags, 0, 256 * sizeof(int), stream);
    fused_kernel<<<257, 1024, 0, stream>>>(q, k, v, U, sl, kqq, vv,
                                           kq_adj, vv_adj, kU_adj, invl,
                                           out, flags);
}